// Round 20
// baseline (666.517 us; speedup 1.0000x reference)
//
#include <hip/hip_runtime.h>
#include <stdint.h>

#define H_DIM 4096
#define I_DIM 11008
#define T_DIM 4096

typedef int i32x4 __attribute__((ext_vector_type(4)));
typedef const void __attribute__((address_space(1))) gvoid_t;
typedef void __attribute__((address_space(3))) svoid_t;

__device__ __forceinline__ void gload_lds16(const void* gsrc, void* ldst) {
    __builtin_amdgcn_global_load_lds((gvoid_t*)gsrc, (svoid_t*)ldst, 16, 0, 0);
}
__device__ __forceinline__ void wait_vmcnt8() {
    asm volatile("s_waitcnt vmcnt(8)" ::: "memory");
}
__device__ __forceinline__ void wait_vmcnt0() {
    asm volatile("s_waitcnt vmcnt(0)" ::: "memory");
}
__device__ __forceinline__ void wait_lgkm0() {
    asm volatile("s_waitcnt lgkmcnt(0)" ::: "memory");
    __builtin_amdgcn_sched_barrier(0);
}
__device__ __forceinline__ void barrier_() {
    asm volatile("s_barrier" ::: "memory");
}

__device__ __forceinline__ uint32_t pack4(int4 v) {
    uint32_t r = (uint32_t)(uint8_t)v.x;
    r |= (uint32_t)(uint8_t)v.y << 8;
    r |= (uint32_t)(uint8_t)v.z << 16;
    r |= (uint32_t)(uint8_t)v.w << 24;
    return r;
}

// int32 -> int8 pack, linear layout (x8 row-major: LDS-staged as A)
__global__ void convert_kernel(const int* __restrict__ src, int8_t* __restrict__ dst,
                               int n4) {
    int idx = blockIdx.x * blockDim.x + threadIdx.x;
    int stride = gridDim.x * blockDim.x;
    for (int i = idx; i < n4; i += stride) {
        int4 v = ((const int4*)src)[i];
        ((uint32_t*)dst)[i] = pack4(v);
    }
}

// int32 [N][K] -> int8 MFMA-fragment order:
// fragment (n>>4, k>>6) is a contiguous 1024B block; within it lane
// ((k&63)>>4)*16 + (n&15) holds bytes k..k+15 at lane*16.
__global__ void convert_frag_kernel(const int* __restrict__ src, int8_t* __restrict__ dst,
                                    int nslots, int kdiv16) {
    const int K = kdiv16 << 4;
    int idx = blockIdx.x * blockDim.x + threadIdx.x;
    int stride = gridDim.x * blockDim.x;
    for (int s = idx; s < nslots; s += stride) {
        const int n_lo = s & 15;
        const int srem = s >> 4;
        const int ks = srem % kdiv16;           // k0 = ks*16
        const int nb = srem / kdiv16;           // n = nb*16 + n_lo
        const int4* p = (const int4*)(src + (size_t)(nb * 16 + n_lo) * K + ks * 16);
        uint4 w;
        w.x = pack4(p[0]); w.y = pack4(p[1]); w.z = pack4(p[2]); w.w = pack4(p[3]);
        const size_t doff = ((size_t)nb * (kdiv16 >> 2) + (ks >> 2)) * 1024
                          + (size_t)(ks & 3) * 256 + (size_t)n_lo * 16;
        *(uint4*)(dst + doff) = w;
    }
}

#define MFMA_I8 __builtin_amdgcn_mfma_i32_16x16x64_i8

// ---------------------------------------------------------------------------
// gateup: champion shell (chunked LDS barriers per 4 iters, fragment-ordered
// direct B, wave-specialized G/U, 4 waves/SIMD, vmcnt-counted, setprio,
// proven swizzle). NEW wave map: each G/U half = 2Mx2N, wave = 64Mx64N
// (acc 4x4 = 64 regs). LDS A-reads halve (dup 8x->4x); B dup 2x is same-CU
// L1-hit. MFMA becomes the top pipe.
// ---------------------------------------------------------------------------
__global__ __launch_bounds__(512, 4)
void gateup_kernel(const int8_t* __restrict__ x8, const int8_t* __restrict__ gwf,
                   const int8_t* __restrict__ uwf,
                   const float* __restrict__ galpha, const float* __restrict__ gbias,
                   const float* __restrict__ ualpha, const float* __restrict__ ubias,
                   const float* __restrict__ scale_p, int8_t* __restrict__ hq)
{
    __shared__ __align__(16) int8_t smem_s[65536];   // 2 chunk-bufs x 32KB

    const int bid = blockIdx.x;
    const int mt = bid & 31;         // M fastest: 32 blocks share each weight panel
    const int nt = bid >> 5;
    const int m0 = mt << 7;
    const int n0 = nt << 7;

    const int tid  = threadIdx.x;
    const int lane = tid & 63;
    const int wid  = tid >> 6;       // 0..7
    const int isU  = wid >> 2;       // 0: G-wave, 1: U-wave
    const int w4   = wid & 3;
    const int mr   = w4 >> 1;        // 0..1  M half (64 rows)
    const int nc   = w4 & 1;         // 0..1  N half (64 cols)
    const int lr   = lane & 15;
    const int rdsw = ((lane >> 4) ^ ((lr >> 1) & 3)) << 4;  // proven swizzle

    const int srow = tid >> 2;                           // 0..127
    const int scol = ((tid & 3) ^ ((tid >> 3) & 3)) << 4;
    const int woff = wid << 10;

    const int8_t* As = x8 + (size_t)(m0 + srow) * H_DIM + scol;
    const int KB64 = H_DIM >> 6;     // 64
    const int8_t* Bsel = isU ? uwf : gwf;
    // wave's 64 cols = 4 fragments starting at (n0>>4) + nc*4
    const int8_t* Bq = Bsel + ((size_t)((n0 >> 4) + nc * 4) * KB64) * 1024 + lane * 16;

    i32x4 acc[4][4];
#pragma unroll
    for (int mf = 0; mf < 4; ++mf)
#pragma unroll
        for (int nf = 0; nf < 4; ++nf) acc[mf][nf] = i32x4{0, 0, 0, 0};

    const int aro = (mr * 64 + lr) * 64 + rdsw;   // + mf*1024 (mf 0..3 = 64 rows)

    // stage one 4-iter chunk (4 x 8KB sub-tiles) into buf b
#define STAGE_CH(b, ch) do { \
        _Pragma("unroll") for (int i_ = 0; i_ < 4; ++i_) \
            gload_lds16(As + (ch) * 256 + i_ * 64, \
                        smem_s + (b) * 32768 + i_ * 8192 + woff); \
    } while (0)

#define BLOAD(BF, tt) do { \
        _Pragma("unroll") for (int nf = 0; nf < 4; ++nf) \
            BF[nf] = *(const i32x4*)(Bq + ((size_t)nf * KB64 + (tt)) * 1024); \
    } while (0)

    // one inner iter: 4 A-frag ds_reads, prefetch next 4 B-frags, 16 MFMA
#define INNER(i_, BF, BFN, c_) do { \
        i32x4 af[4]; \
        _Pragma("unroll") for (int mf = 0; mf < 4; ++mf) \
            af[mf] = *(const i32x4*)(smem_s + ((c_) & 1) * 32768 + (i_) * 8192 \
                                     + aro + mf * 1024); \
        BLOAD(BFN, ((c_) * 4 + (i_) + 1) & (NKT - 1)); \
        __builtin_amdgcn_s_setprio(1); \
        _Pragma("unroll") for (int mf = 0; mf < 4; ++mf) \
        _Pragma("unroll") for (int nf = 0; nf < 4; ++nf) \
            acc[mf][nf] = MFMA_I8(af[mf], BF[nf], acc[mf][nf], 0, 0, 0); \
        __builtin_amdgcn_s_setprio(0); \
    } while (0)

    const int NKT = H_DIM / 64;      // 64
    const int NC  = NKT / 4;         // 16 chunks (power of 2)
    i32x4 bfA[4], bfB[4];
    STAGE_CH(0, 0);
    STAGE_CH(1, 1);
    BLOAD(bfA, 0);                   // queue: S0x4, S1x4, Bx4 = 12

    for (int c = 0; c < NC; ++c) {
        wait_vmcnt8();               // certifies chunk c (8 newest: stage(c+1)+bfA)
        barrier_();
        INNER(0, bfA, bfB, c);
        INNER(1, bfB, bfA, c);
        INNER(2, bfA, bfB, c);
        INNER(3, bfB, bfA, c);
        wait_lgkm0();
        barrier_();                  // all waves done reading buf[c&1]
        STAGE_CH(c & 1, (c + 2) & (NC - 1));
    }
#undef INNER
#undef BLOAD
#undef STAGE_CH
    wait_vmcnt0();                   // drain tail prefetches
    barrier_();                      // LDS reusable for exchange

    // ---- exchange U-acc -> G-waves, SwiGLU epilogue (two mf-halves) ----
    const float inv_scale = 1.0f / (*scale_p);
#pragma unroll
    for (int h = 0; h < 2; ++h) {
        if (isU) {
#pragma unroll
            for (int mq = 0; mq < 2; ++mq)
#pragma unroll
                for (int nf = 0; nf < 4; ++nf)
                    *(i32x4*)(smem_s + w4 * 8192 + mq * 4096 + nf * 1024 + lane * 16)
                        = acc[h * 2 + mq][nf];
        }
        barrier_();
        if (!isU) {
#pragma unroll
            for (int nf = 0; nf < 4; ++nf) {
                const int col = n0 + nc * 64 + nf * 16 + lr;
                const float gA = galpha[col], gB = gbias[col];
                const float uA = ualpha[col], uB = ubias[col];
#pragma unroll
                for (int mq = 0; mq < 2; ++mq) {
                    i32x4 uacc = *(const i32x4*)(smem_s + w4 * 8192 + mq * 4096
                                                 + nf * 1024 + lane * 16);
                    const int row0 = m0 + mr * 64 + (h * 2 + mq) * 16 + (lane >> 4) * 4;
#pragma unroll
                    for (int j = 0; j < 4; ++j) {
                        float g = (float)acc[h * 2 + mq][nf][j] * gA + gB;
                        float u = (float)uacc[j] * uA + uB;
                        float s = 1.0f / (1.0f + __expf(-g));
                        float hh = g * s * u;
                        float qv = rintf(hh * inv_scale);
                        qv = fminf(127.0f, fmaxf(-128.0f, qv));
                        hq[(size_t)(row0 + j) * I_DIM + col] = (int8_t)qv;
                    }
                }
            }
        }
        barrier_();
    }
}

// ---------------------------------------------------------------------------
// down: tile 128x256, 8 waves as 2M x 4N, wave = 64Mx64N (acc 64). A (hq)
// via chunked LDS, B (dwf fragment-ordered) direct. NC=43. Same schedule.
// ---------------------------------------------------------------------------
__global__ __launch_bounds__(512, 4)
void down_kernel(const int8_t* __restrict__ hq, const int8_t* __restrict__ dwf,
                 const float* __restrict__ dalpha, const float* __restrict__ dbias,
                 float* __restrict__ out)
{
    __shared__ __align__(16) int8_t smem_d[65536];   // 2 chunk-bufs x 32KB

    const int bid = blockIdx.x;
    const int mt = bid & 31;         // 32 M tiles of 128 (M fastest)
    const int nt = bid >> 5;         // 16 N tiles of 256
    const int m0 = mt << 7;
    const int n0 = nt << 8;

    const int tid  = threadIdx.x;
    const int lane = tid & 63;
    const int wid  = tid >> 6;       // 0..7
    const int mr   = wid >> 2;       // 0..1 M half
    const int nc   = wid & 3;        // 0..3 N quarter (64 cols each)
    const int lr   = lane & 15;
    const int rdsw = ((lane >> 4) ^ ((lr >> 1) & 3)) << 4;

    const int srow = tid >> 2;
    const int scol = ((tid & 3) ^ ((tid >> 3) & 3)) << 4;
    const int woff = wid << 10;

    const int8_t* Ap = hq + (size_t)(m0 + srow) * I_DIM + scol;
    const int KB64 = I_DIM >> 6;     // 172
    const int8_t* Bq = dwf + ((size_t)((n0 >> 4) + nc * 4) * KB64) * 1024 + lane * 16;

    i32x4 acc[4][4];
#pragma unroll
    for (int mf = 0; mf < 4; ++mf)
#pragma unroll
        for (int nf = 0; nf < 4; ++nf) acc[mf][nf] = i32x4{0, 0, 0, 0};

    const int aro = (mr * 64 + lr) * 64 + rdsw;   // + mf*1024

#define STAGE_CH(b, ch) do { \
        _Pragma("unroll") for (int i_ = 0; i_ < 4; ++i_) \
            gload_lds16(Ap + (size_t)(ch) * 256 + i_ * 64, \
                        smem_d + (b) * 32768 + i_ * 8192 + woff); \
    } while (0)

#define BLOAD(BF, tt) do { \
        _Pragma("unroll") for (int nf = 0; nf < 4; ++nf) \
            BF[nf] = *(const i32x4*)(Bq + ((size_t)nf * KB64 + (tt)) * 1024); \
    } while (0)

#define INNER(i_, BF, BFN, c_) do { \
        i32x4 af[4]; \
        _Pragma("unroll") for (int mf = 0; mf < 4; ++mf) \
            af[mf] = *(const i32x4*)(smem_d + ((c_) & 1) * 32768 + (i_) * 8192 \
                                     + aro + mf * 1024); \
        BLOAD(BFN, ((c_) * 4 + (i_) + 1) % NKT); \
        __builtin_amdgcn_s_setprio(1); \
        _Pragma("unroll") for (int mf = 0; mf < 4; ++mf) \
        _Pragma("unroll") for (int nf = 0; nf < 4; ++nf) \
            acc[mf][nf] = MFMA_I8(af[mf], BF[nf], acc[mf][nf], 0, 0, 0); \
        __builtin_amdgcn_s_setprio(0); \
    } while (0)

    const int NKT = I_DIM / 64;      // 172
    const int NC  = NKT / 4;         // 43 chunks
    i32x4 bfA[4], bfB[4];
    STAGE_CH(0, 0);
    STAGE_CH(1, 1);
    BLOAD(bfA, 0);

    for (int c = 0; c < NC; ++c) {
        wait_vmcnt8();
        barrier_();
        INNER(0, bfA, bfB, c);
        INNER(1, bfB, bfA, c);
        INNER(2, bfA, bfB, c);
        INNER(3, bfB, bfA, c);
        wait_lgkm0();
        barrier_();
        STAGE_CH(c & 1, (c + 2) % NC);
    }
#undef INNER
#undef BLOAD
#undef STAGE_CH
    wait_vmcnt0();

    // ---- epilogue: dequant to fp32 ----
#pragma unroll
    for (int nf = 0; nf < 4; ++nf) {
        const int col = n0 + nc * 64 + nf * 16 + lr;
        const float dA = dalpha[col], dB = dbias[col];
#pragma unroll
        for (int mf = 0; mf < 4; ++mf) {
            const int row0 = m0 + mr * 64 + mf * 16 + (lane >> 4) * 4;
#pragma unroll
            for (int j = 0; j < 4; ++j) {
                out[(size_t)(row0 + j) * H_DIM + col] = (float)acc[mf][nf][j] * dA + dB;
            }
        }
    }
}

extern "C" void kernel_launch(void* const* d_in, const int* in_sizes, int n_in,
                              void* d_out, int out_size, void* d_ws, size_t ws_size,
                              hipStream_t stream) {
    const int* x32  = (const int*)d_in[0];
    const int* gw32 = (const int*)d_in[1];
    const int* uw32 = (const int*)d_in[2];
    const int* dw32 = (const int*)d_in[3];
    const float* ga = (const float*)d_in[4];
    const float* gb = (const float*)d_in[5];
    const float* ua = (const float*)d_in[6];
    const float* ub = (const float*)d_in[7];
    const float* da = (const float*)d_in[8];
    const float* db = (const float*)d_in[9];
    const float* sc = (const float*)d_in[10];
    float* out = (float*)d_out;

    const size_t SZ_X8 = (size_t)T_DIM * H_DIM;
    const size_t SZ_W  = (size_t)I_DIM * H_DIM;
    const size_t SZ_HQ = (size_t)T_DIM * I_DIM;

    int8_t* gwf = (int8_t*)d_ws;              // reused for dwf later
    int8_t* uwf = gwf + SZ_W;
    int8_t* hq  = uwf + SZ_W;
    int8_t* x8  = hq + SZ_HQ;

    convert_kernel<<<dim3(2048), dim3(256), 0, stream>>>(x32, x8, (int)(SZ_X8 / 4));
    convert_frag_kernel<<<dim3(2048), dim3(256), 0, stream>>>(
        gw32, gwf, (int)(SZ_W / 16), H_DIM / 16);
    convert_frag_kernel<<<dim3(2048), dim3(256), 0, stream>>>(
        uw32, uwf, (int)(SZ_W / 16), H_DIM / 16);
    gateup_kernel<<<dim3(32 * 86), dim3(512), 0, stream>>>(
        x8, gwf, uwf, ga, gb, ua, ub, sc, hq);
    int8_t* dwf = gwf;   // overwrite gate weights (stream-ordered after gateup)
    convert_frag_kernel<<<dim3(2048), dim3(256), 0, stream>>>(
        dw32, dwf, (int)(SZ_W / 16), I_DIM / 16);
    down_kernel<<<dim3(32 * 16), dim3(512), 0, stream>>>(hq, dwf, da, db, out);
}

// Round 21
// 626.265 us; speedup vs baseline: 1.0643x; 1.0643x over previous
//
#include <hip/hip_runtime.h>
#include <stdint.h>

#define H_DIM 4096
#define I_DIM 11008
#define T_DIM 4096

typedef int i32x4 __attribute__((ext_vector_type(4)));
typedef const void __attribute__((address_space(1))) gvoid_t;
typedef void __attribute__((address_space(3))) svoid_t;

__device__ __forceinline__ void gload_lds16(const void* gsrc, void* ldst) {
    __builtin_amdgcn_global_load_lds((gvoid_t*)gsrc, (svoid_t*)ldst, 16, 0, 0);
}
__device__ __forceinline__ void wait_vmcnt6() {
    asm volatile("s_waitcnt vmcnt(6)" ::: "memory");
}
__device__ __forceinline__ void wait_vmcnt0() {
    asm volatile("s_waitcnt vmcnt(0)" ::: "memory");
}
__device__ __forceinline__ void wait_lgkm0() {
    asm volatile("s_waitcnt lgkmcnt(0)" ::: "memory");
    __builtin_amdgcn_sched_barrier(0);
}
__device__ __forceinline__ void barrier_() {
    asm volatile("s_barrier" ::: "memory");
}

__device__ __forceinline__ uint32_t pack4(int4 v) {
    uint32_t r = (uint32_t)(uint8_t)v.x;
    r |= (uint32_t)(uint8_t)v.y << 8;
    r |= (uint32_t)(uint8_t)v.z << 16;
    r |= (uint32_t)(uint8_t)v.w << 24;
    return r;
}

// int32 -> int8 pack, linear layout (x8 row-major: LDS-staged as A)
__global__ void convert_kernel(const int* __restrict__ src, int8_t* __restrict__ dst,
                               int n4) {
    int idx = blockIdx.x * blockDim.x + threadIdx.x;
    int stride = gridDim.x * blockDim.x;
    for (int i = idx; i < n4; i += stride) {
        int4 v = ((const int4*)src)[i];
        ((uint32_t*)dst)[i] = pack4(v);
    }
}

// int32 [N][K] -> int8 MFMA-fragment order:
// fragment (n>>4, k>>6) is a contiguous 1024B block; within it lane
// ((k&63)>>4)*16 + (n&15) holds bytes k..k+15 at lane*16.
__global__ void convert_frag_kernel(const int* __restrict__ src, int8_t* __restrict__ dst,
                                    int nslots, int kdiv16) {
    const int K = kdiv16 << 4;
    int idx = blockIdx.x * blockDim.x + threadIdx.x;
    int stride = gridDim.x * blockDim.x;
    for (int s = idx; s < nslots; s += stride) {
        const int n_lo = s & 15;
        const int srem = s >> 4;
        const int ks = srem % kdiv16;           // k0 = ks*16
        const int nb = srem / kdiv16;           // n = nb*16 + n_lo
        const int4* p = (const int4*)(src + (size_t)(nb * 16 + n_lo) * K + ks * 16);
        uint4 w;
        w.x = pack4(p[0]); w.y = pack4(p[1]); w.z = pack4(p[2]); w.w = pack4(p[3]);
        const size_t doff = ((size_t)nb * (kdiv16 >> 2) + (ks >> 2)) * 1024
                          + (size_t)(ks & 3) * 256 + (size_t)n_lo * 16;
        *(uint4*)(dst + doff) = w;
    }
}

#define MFMA_I8 __builtin_amdgcn_mfma_i32_16x16x64_i8

// ---------------------------------------------------------------------------
// gateup (CHAMPION, R19): tile 128x128, chunked LDS (barriers per 4 iters),
// fragment-ordered direct B, wave-specialized G/U. Wave map: each wave =
// 128M x 32N (1M x 4N among its group) -> zero B duplication. acc 64 regs ->
// 4 waves/SIMD. Counted vmcnt(6), setprio, proven swizzle.
// ---------------------------------------------------------------------------
__global__ __launch_bounds__(512, 4)
void gateup_kernel(const int8_t* __restrict__ x8, const int8_t* __restrict__ gwf,
                   const int8_t* __restrict__ uwf,
                   const float* __restrict__ galpha, const float* __restrict__ gbias,
                   const float* __restrict__ ualpha, const float* __restrict__ ubias,
                   const float* __restrict__ scale_p, int8_t* __restrict__ hq)
{
    __shared__ __align__(16) int8_t smem_s[65536];   // 2 chunk-bufs x 32KB

    const int bid = blockIdx.x;
    const int mt = bid & 31;         // M fastest: 32 blocks share each weight panel
    const int nt = bid >> 5;
    const int m0 = mt << 7;
    const int n0 = nt << 7;

    const int tid  = threadIdx.x;
    const int lane = tid & 63;
    const int wid  = tid >> 6;       // 0..7
    const int isU  = wid >> 2;       // 0: G-wave, 1: U-wave
    const int w4   = wid & 3;        // wave column 0..3 (32 cols each)
    const int lr   = lane & 15;
    const int rdsw = ((lane >> 4) ^ ((lr >> 1) & 3)) << 4;  // proven swizzle

    const int srow = tid >> 2;                           // 0..127
    const int scol = ((tid & 3) ^ ((tid >> 3) & 3)) << 4;
    const int woff = wid << 10;

    const int8_t* As = x8 + (size_t)(m0 + srow) * H_DIM + scol;
    const int KB64 = H_DIM >> 6;     // 64
    const int8_t* Bsel = isU ? uwf : gwf;
    // wave's 32 cols = 2 fragments starting at (n0>>4) + w4*2
    const int8_t* Bq = Bsel + ((size_t)((n0 >> 4) + w4 * 2) * KB64) * 1024 + lane * 16;

    i32x4 acc[8][2];
#pragma unroll
    for (int mf = 0; mf < 8; ++mf)
#pragma unroll
        for (int nf = 0; nf < 2; ++nf) acc[mf][nf] = i32x4{0, 0, 0, 0};

    const int aro = lr * 64 + rdsw;  // + mf*1024 (mf 0..7 covers 128 rows)

    // stage one 4-iter chunk (4 x 8KB sub-tiles) into buf b
#define STAGE_CH(b, ch) do { \
        _Pragma("unroll") for (int i_ = 0; i_ < 4; ++i_) \
            gload_lds16(As + (ch) * 256 + i_ * 64, \
                        smem_s + (b) * 32768 + i_ * 8192 + woff); \
    } while (0)

#define BLOAD(BF, tt) do { \
        _Pragma("unroll") for (int nf = 0; nf < 2; ++nf) \
            BF[nf] = *(const i32x4*)(Bq + ((size_t)nf * KB64 + (tt)) * 1024); \
    } while (0)

    // one inner iter: 8 A-frag ds_reads, prefetch next 2 B-frags, 16 MFMA
#define INNER(i_, BF, BFN, c_) do { \
        i32x4 af[8]; \
        _Pragma("unroll") for (int mf = 0; mf < 8; ++mf) \
            af[mf] = *(const i32x4*)(smem_s + ((c_) & 1) * 32768 + (i_) * 8192 \
                                     + aro + mf * 1024); \
        BLOAD(BFN, ((c_) * 4 + (i_) + 1) & (NKT - 1)); \
        __builtin_amdgcn_s_setprio(1); \
        _Pragma("unroll") for (int mf = 0; mf < 8; ++mf) \
        _Pragma("unroll") for (int nf = 0; nf < 2; ++nf) \
            acc[mf][nf] = MFMA_I8(af[mf], BF[nf], acc[mf][nf], 0, 0, 0); \
        __builtin_amdgcn_s_setprio(0); \
    } while (0)

    const int NKT = H_DIM / 64;      // 64
    const int NC  = NKT / 4;         // 16 chunks (power of 2)
    i32x4 bfA[2], bfB[2];
    STAGE_CH(0, 0);
    STAGE_CH(1, 1);
    BLOAD(bfA, 0);                   // queue: S0x4, S1x4, Bx2 = 10

    for (int c = 0; c < NC; ++c) {
        wait_vmcnt6();               // certifies chunk c (<=6 newest left)
        barrier_();
        INNER(0, bfA, bfB, c);
        INNER(1, bfB, bfA, c);
        INNER(2, bfA, bfB, c);
        INNER(3, bfB, bfA, c);
        wait_lgkm0();
        barrier_();                  // all waves done reading buf[c&1]
        STAGE_CH(c & 1, (c + 2) & (NC - 1));
    }
#undef INNER
#undef BLOAD
#undef STAGE_CH
    wait_vmcnt0();                   // drain tail prefetches
    barrier_();                      // LDS reusable for exchange

    // ---- exchange U-acc -> G-waves, SwiGLU epilogue (two mf-halves) ----
    const float inv_scale = 1.0f / (*scale_p);
#pragma unroll
    for (int h = 0; h < 2; ++h) {
        if (isU) {
#pragma unroll
            for (int mq = 0; mq < 4; ++mq)
#pragma unroll
                for (int nf = 0; nf < 2; ++nf)
                    *(i32x4*)(smem_s + w4 * 8192 + mq * 2048 + nf * 1024 + lane * 16)
                        = acc[h * 4 + mq][nf];
        }
        barrier_();
        if (!isU) {
#pragma unroll
            for (int nf = 0; nf < 2; ++nf) {
                const int col = n0 + w4 * 32 + nf * 16 + lr;
                const float gA = galpha[col], gB = gbias[col];
                const float uA = ualpha[col], uB = ubias[col];
#pragma unroll
                for (int mq = 0; mq < 4; ++mq) {
                    i32x4 uacc = *(const i32x4*)(smem_s + w4 * 8192 + mq * 2048
                                                 + nf * 1024 + lane * 16);
                    const int row0 = m0 + (h * 4 + mq) * 16 + (lane >> 4) * 4;
#pragma unroll
                    for (int j = 0; j < 4; ++j) {
                        float g = (float)acc[h * 4 + mq][nf][j] * gA + gB;
                        float u = (float)uacc[j] * uA + uB;
                        float s = 1.0f / (1.0f + __expf(-g));
                        float hh = g * s * u;
                        float qv = rintf(hh * inv_scale);
                        qv = fminf(127.0f, fmaxf(-128.0f, qv));
                        hq[(size_t)(row0 + j) * I_DIM + col] = (int8_t)qv;
                    }
                }
            }
        }
        barrier_();
    }
}

// ---------------------------------------------------------------------------
// down: tile 128x256, 8 waves each 128M x 32N (1M x 8N) -> zero B dup.
// A (hq) via chunked LDS, B (dwf fragment-ordered) direct. NC=43.
// ---------------------------------------------------------------------------
__global__ __launch_bounds__(512, 4)
void down_kernel(const int8_t* __restrict__ hq, const int8_t* __restrict__ dwf,
                 const float* __restrict__ dalpha, const float* __restrict__ dbias,
                 float* __restrict__ out)
{
    __shared__ __align__(16) int8_t smem_d[65536];   // 2 chunk-bufs x 32KB

    const int bid = blockIdx.x;
    const int mt = bid & 31;         // 32 M tiles of 128 (M fastest)
    const int nt = bid >> 5;         // 16 N tiles of 256
    const int m0 = mt << 7;
    const int n0 = nt << 8;

    const int tid  = threadIdx.x;
    const int lane = tid & 63;
    const int wid  = tid >> 6;       // 0..7: wave column (32 cols each)
    const int lr   = lane & 15;
    const int rdsw = ((lane >> 4) ^ ((lr >> 1) & 3)) << 4;

    const int srow = tid >> 2;
    const int scol = ((tid & 3) ^ ((tid >> 3) & 3)) << 4;
    const int woff = wid << 10;

    const int8_t* Ap = hq + (size_t)(m0 + srow) * I_DIM + scol;
    const int KB64 = I_DIM >> 6;     // 172
    const int8_t* Bq = dwf + ((size_t)((n0 >> 4) + wid * 2) * KB64) * 1024 + lane * 16;

    i32x4 acc[8][2];
#pragma unroll
    for (int mf = 0; mf < 8; ++mf)
#pragma unroll
        for (int nf = 0; nf < 2; ++nf) acc[mf][nf] = i32x4{0, 0, 0, 0};

    const int aro = lr * 64 + rdsw;  // + mf*1024

#define STAGE_CH(b, ch) do { \
        _Pragma("unroll") for (int i_ = 0; i_ < 4; ++i_) \
            gload_lds16(Ap + (size_t)(ch) * 256 + i_ * 64, \
                        smem_d + (b) * 32768 + i_ * 8192 + woff); \
    } while (0)

#define BLOAD(BF, tt) do { \
        _Pragma("unroll") for (int nf = 0; nf < 2; ++nf) \
            BF[nf] = *(const i32x4*)(Bq + ((size_t)nf * KB64 + (tt)) * 1024); \
    } while (0)

#define INNER(i_, BF, BFN, c_) do { \
        i32x4 af[8]; \
        _Pragma("unroll") for (int mf = 0; mf < 8; ++mf) \
            af[mf] = *(const i32x4*)(smem_d + ((c_) & 1) * 32768 + (i_) * 8192 \
                                     + aro + mf * 1024); \
        BLOAD(BFN, ((c_) * 4 + (i_) + 1) % NKT); \
        __builtin_amdgcn_s_setprio(1); \
        _Pragma("unroll") for (int mf = 0; mf < 8; ++mf) \
        _Pragma("unroll") for (int nf = 0; nf < 2; ++nf) \
            acc[mf][nf] = MFMA_I8(af[mf], BF[nf], acc[mf][nf], 0, 0, 0); \
        __builtin_amdgcn_s_setprio(0); \
    } while (0)

    const int NKT = I_DIM / 64;      // 172
    const int NC  = NKT / 4;         // 43 chunks
    i32x4 bfA[2], bfB[2];
    STAGE_CH(0, 0);
    STAGE_CH(1, 1);
    BLOAD(bfA, 0);

    for (int c = 0; c < NC; ++c) {
        wait_vmcnt6();
        barrier_();
        INNER(0, bfA, bfB, c);
        INNER(1, bfB, bfA, c);
        INNER(2, bfA, bfB, c);
        INNER(3, bfB, bfA, c);
        wait_lgkm0();
        barrier_();
        STAGE_CH(c & 1, (c + 2) % NC);
    }
#undef INNER
#undef BLOAD
#undef STAGE_CH
    wait_vmcnt0();

    // ---- epilogue: dequant to fp32 ----
#pragma unroll
    for (int nf = 0; nf < 2; ++nf) {
        const int col = n0 + wid * 32 + nf * 16 + lr;
        const float dA = dalpha[col], dB = dbias[col];
#pragma unroll
        for (int mf = 0; mf < 8; ++mf) {
            const int row0 = m0 + mf * 16 + (lane >> 4) * 4;
#pragma unroll
            for (int j = 0; j < 4; ++j) {
                out[(size_t)(row0 + j) * H_DIM + col] = (float)acc[mf][nf][j] * dA + dB;
            }
        }
    }
}

extern "C" void kernel_launch(void* const* d_in, const int* in_sizes, int n_in,
                              void* d_out, int out_size, void* d_ws, size_t ws_size,
                              hipStream_t stream) {
    const int* x32  = (const int*)d_in[0];
    const int* gw32 = (const int*)d_in[1];
    const int* uw32 = (const int*)d_in[2];
    const int* dw32 = (const int*)d_in[3];
    const float* ga = (const float*)d_in[4];
    const float* gb = (const float*)d_in[5];
    const float* ua = (const float*)d_in[6];
    const float* ub = (const float*)d_in[7];
    const float* da = (const float*)d_in[8];
    const float* db = (const float*)d_in[9];
    const float* sc = (const float*)d_in[10];
    float* out = (float*)d_out;

    const size_t SZ_X8 = (size_t)T_DIM * H_DIM;
    const size_t SZ_W  = (size_t)I_DIM * H_DIM;
    const size_t SZ_HQ = (size_t)T_DIM * I_DIM;

    int8_t* gwf = (int8_t*)d_ws;              // reused for dwf later
    int8_t* uwf = gwf + SZ_W;
    int8_t* hq  = uwf + SZ_W;
    int8_t* x8  = hq + SZ_HQ;

    convert_kernel<<<dim3(2048), dim3(256), 0, stream>>>(x32, x8, (int)(SZ_X8 / 4));
    convert_frag_kernel<<<dim3(2048), dim3(256), 0, stream>>>(
        gw32, gwf, (int)(SZ_W / 16), H_DIM / 16);
    convert_frag_kernel<<<dim3(2048), dim3(256), 0, stream>>>(
        uw32, uwf, (int)(SZ_W / 16), H_DIM / 16);
    gateup_kernel<<<dim3(32 * 86), dim3(512), 0, stream>>>(
        x8, gwf, uwf, ga, gb, ua, ub, sc, hq);
    int8_t* dwf = gwf;   // overwrite gate weights (stream-ordered after gateup)
    convert_frag_kernel<<<dim3(2048), dim3(256), 0, stream>>>(
        dw32, dwf, (int)(SZ_W / 16), I_DIM / 16);
    down_kernel<<<dim3(32 * 16), dim3(512), 0, stream>>>(hq, dwf, da, db, out);
}